// Round 12
// baseline (85.654 us; speedup 1.0000x reference)
//
#include <hip/hip_runtime.h>
#include <hip/hip_bf16.h>
#include <cmath>
#include <cstdint>

#define Bsz   4096
#define INsz  512
#define OUTsz 512
#define NRING 16
#define KTOT  8704          /* IN*(NR+1): residual folded in as 17th slot */
#define SPLITK 8
#define NPH   17            /* rings 0..15 + residual; K=64 each (the 64 i's) */

using short8 = __attribute__((ext_vector_type(8))) short;
using f32x4  = __attribute__((ext_vector_type(4))) float;

struct RC {
  float Fr[NRING];    // fract(rev0_r)
  float K2, SQ, pad0, pad1;  // h=K2*xc*rcp(wl); A' = rcp(cos2pi(fract(h+Fr))+SQ)
};

__device__ __forceinline__ unsigned short f2bf(float f) {
  __hip_bfloat16 h = __float2bfloat16(f);               // native cvt (RNE)
  return *reinterpret_cast<unsigned short*>(&h);
}
__device__ __forceinline__ float bf2f(unsigned short u) {
  union { unsigned int u; float f; } v; v.u = (unsigned int)u << 16;
  return v.f;
}
__device__ __forceinline__ float fastrcp(float x) {
#if __has_builtin(__builtin_amdgcn_rcpf)
  return __builtin_amdgcn_rcpf(x);
#else
  return 1.0f / x;
#endif
}
__device__ __forceinline__ float fastfract(float x) {
#if __has_builtin(__builtin_amdgcn_fractf)
  return __builtin_amdgcn_fractf(x);
#else
  return x - floorf(x);
#endif
}
__device__ __forceinline__ float cos2pi(float fr) {
#if __has_builtin(__builtin_amdgcn_cosf)
  return __builtin_amdgcn_cosf(fr);
#else
  return __cosf(fr * 6.28318530717958647692f);
#endif
}

__device__ __forceinline__ void gl_lds16(const void* g, void* l) {
  __builtin_amdgcn_global_load_lds(
      (const __attribute__((address_space(1))) void*)g,
      (__attribute__((address_space(3))) void*)l, 16, 0, 0);
}

// ---- pack B'^T: [OUT][KTOT] bf16, k = n*512 + i; also bias[o] = sum coeffs ----
__global__ __launch_bounds__(512) void pack_b_kernel(
    const float* __restrict__ coeffs, const float* __restrict__ bw,
    unsigned short* __restrict__ Bt, float* __restrict__ bias, float PQ) {
  __shared__ float red[8];
  const int o = blockIdx.x;        // 512 blocks
  const int i = threadIdx.x;       // 512 threads
  const float* cp = coeffs + ((size_t)i * OUTsz + o) * NRING;  // 64B contiguous
  unsigned short* row = Bt + (size_t)o * KTOT + i;
  float s = 0.0f;
#pragma unroll
  for (int j = 0; j < 4; ++j) {
    f32x4 v = *reinterpret_cast<const f32x4*>(cp + j * 4);
#pragma unroll
    for (int e = 0; e < 4; ++e) {
      const int n = j * 4 + e;
      s += v[e];
      row[(size_t)n * INsz] = f2bf(PQ * v[e]);
    }
  }
  row[(size_t)NRING * INsz] = f2bf(bw[(size_t)i * OUTsz + o]);  // residual unscaled
#pragma unroll
  for (int off = 32; off > 0; off >>= 1) s += __shfl_down(s, off);
  const int w = i >> 6;
  if ((i & 63) == 0) red[w] = s;
  __syncthreads();
  if (i == 0) {
    float t = 0.0f;
#pragma unroll
    for (int k = 0; k < 8; ++k) t += red[k];
    bias[o] = t;
  }
}

// ---- fused basis-gen + split-K bf16 MFMA GEMM ----
// Block 256x256 out, 8 waves (2M x 4N, wave tile 128x64 -> 0.75x LDS bytes/FLOP
// vs 64x64), splitK=8 (block owns 64 i's), grid 256 = 1 block/CU.
// LDS 160KB: A dbuf 2x32KB ([256][64] swizzled) + B 3-deep 3x32KB.
// 17 phases (ring 0..15 + residual), ONE barrier/phase, counted vmcnt(4).
// plain launch_bounds(512): 256-VGPR cap; demand ~240 (acc128+hrev32+frag48).
__global__ __launch_bounds__(512) void gemm_fused_kernel(
    const float* __restrict__ x, const unsigned short* __restrict__ Bt,
    unsigned short* __restrict__ part, RC rc) {
  extern __shared__ char smem[];
  char* smA = smem;            // 2 x 32768
  char* smB = smem + 65536;    // 3 x 32768
  const int tid  = threadIdx.x;
  const int lane = tid & 63;
  const int w    = tid >> 6;
  const int bid  = blockIdx.x;
  const int combo = bid & 15;        // (cb,ks); same combo -> same XCD
  const int rb   = bid >> 4;         // 0..15
  const int cb   = combo & 1, ks = combo >> 1;   // cb 0..1, ks 0..7
  const int brow = rb * 256, bcol = cb * 256;

  // --- A-gen ownership: row r (0..255), i-half ih (32 of the 64 i's) ---
  const int r  = tid & 255;
  const int ih = tid >> 8;           // 0..1
  int wb[4];
#pragma unroll
  for (int g = 0; g < 4; ++g)
    wb[g] = r * 128 + (((ih * 4 + g) ^ (r & 7)) * 16);
  const float* gx = x + (size_t)(brow + r) * INsz + ks * 64 + ih * 32;

  // --- B staging: pre-swizzled per-lane global source, linear LDS dest ---
  const int cg = (lane & 7) ^ ((lane >> 3) & 7);
  const unsigned short* gb0 = Bt + (size_t)(bcol + w * 8 + (lane >> 3)) * KTOT
                                 + ks * 64 + cg * 8;

  // --- fragment read geometry: 8 waves = 2M x 4N, wave tile 128x64 ---
  const int wr = w >> 2, wc = w & 3;
  const int l7 = lane & 7;
  const int rowA = wr * 128 + (lane & 15);
  const int rowB = wc * 64 + (lane & 15);
  const int oct0 = (((lane >> 4) + 0) ^ l7) * 16;
  const int oct1 = (((lane >> 4) + 4) ^ l7) * 16;

  // --- prologue: load x, compute hrev[32] (1 reg per owned element) ---
  float hrev[32];
#pragma unroll
  for (int j = 0; j < 8; ++j) {
    f32x4 v = *reinterpret_cast<const f32x4*>(gx + j * 4);
#pragma unroll
    for (int e = 0; e < 4; ++e) {
      float xc = fminf(fmaxf(v[e], -1.0f), 1.0f);
      float wl = __builtin_fmaf(xc, 4.0e-9f, 1550.0e-9f);
      hrev[j * 4 + e] = rc.K2 * xc * fastrcp(wl);
    }
  }

  auto STAGE = [&](int p) {   // 4 gl_lds rounds: 256 B-rows x 64 k of ring p
    char* ldst = smB + (p % 3) * 32768 + w * 1024;
    const unsigned short* src = gb0 + (size_t)p * 512;
#pragma unroll
    for (int iss = 0; iss < 4; ++iss)
      gl_lds16(src + (size_t)iss * 64 * KTOT, ldst + iss * 8192);
  };
  auto GENA = [&](int ring) {  // A-tile (ring) into smA[ring&1] (other buffer)
    char* dst = smA + (ring & 1) * 32768;
    if (ring < NRING) {
      const float Frn = rc.Fr[ring];
#pragma unroll
      for (int g = 0; g < 4; ++g) {
        short8 wv;
#pragma unroll
        for (int e = 0; e < 8; ++e) {
          float t = fastfract(hrev[g * 8 + e] + Frn);
          wv[e] = (short)f2bf(fastrcp(cos2pi(t) + rc.SQ));
        }
        *reinterpret_cast<short8*>(dst + wb[g]) = wv;
      }
    } else {                   // residual: reload raw x from L2, pack bf16
#pragma unroll
      for (int g = 0; g < 4; ++g) {
        f32x4 v0 = *reinterpret_cast<const f32x4*>(gx + g * 8);
        f32x4 v1 = *reinterpret_cast<const f32x4*>(gx + g * 8 + 4);
        short8 wv;
#pragma unroll
        for (int e = 0; e < 4; ++e) {
          wv[e]     = (short)f2bf(v0[e]);
          wv[4 + e] = (short)f2bf(v1[e]);
        }
        *reinterpret_cast<short8*>(dst + wb[g]) = wv;
      }
    }
  };

  f32x4 acc[8][4];
#pragma unroll
  for (int m = 0; m < 8; ++m)
#pragma unroll
    for (int q = 0; q < 4; ++q) acc[m][q] = (f32x4){0.f, 0.f, 0.f, 0.f};

  STAGE(0); STAGE(1);
  GENA(0);
  asm volatile("s_waitcnt vmcnt(4) lgkmcnt(0)" ::: "memory");
  __builtin_amdgcn_s_barrier();
  __builtin_amdgcn_sched_barrier(0);

#pragma unroll
  for (int p = 0; p < NPH; ++p) {
    const char* bA = smA + (p & 1) * 32768;
    const char* bB = smB + (p % 3) * 32768;
    // ---- kk0: reads -> MFMA (STAGE issued between) ----
    {
      short8 af[8], bv[4];
#pragma unroll
      for (int m = 0; m < 8; ++m)
        af[m] = *reinterpret_cast<const short8*>(bA + (rowA + m * 16) * 128 + oct0);
#pragma unroll
      for (int q = 0; q < 4; ++q)
        bv[q] = *reinterpret_cast<const short8*>(bB + (rowB + q * 16) * 128 + oct0);
      if (p + 2 < NPH) STAGE(p + 2);
      __builtin_amdgcn_s_setprio(1);
#pragma unroll
      for (int m = 0; m < 8; ++m)
#pragma unroll
        for (int q = 0; q < 4; ++q)
          acc[m][q] = __builtin_amdgcn_mfma_f32_16x16x32_bf16(af[m], bv[q], acc[m][q], 0, 0, 0);
      __builtin_amdgcn_s_setprio(0);
    }
    // ---- kk1: reads -> GENA(p+1) into other A-buf -> MFMA ----
    {
      short8 af[8], bv[4];
#pragma unroll
      for (int m = 0; m < 8; ++m)
        af[m] = *reinterpret_cast<const short8*>(bA + (rowA + m * 16) * 128 + oct1);
#pragma unroll
      for (int q = 0; q < 4; ++q)
        bv[q] = *reinterpret_cast<const short8*>(bB + (rowB + q * 16) * 128 + oct1);
      if (p + 1 < NPH) GENA(p + 1);
      __builtin_amdgcn_s_setprio(1);
#pragma unroll
      for (int m = 0; m < 8; ++m)
#pragma unroll
        for (int q = 0; q < 4; ++q)
          acc[m][q] = __builtin_amdgcn_mfma_f32_16x16x32_bf16(af[m], bv[q], acc[m][q], 0, 0, 0);
      __builtin_amdgcn_s_setprio(0);
    }
    if (p + 1 < NPH) {
      if (p + 2 < NPH) {
        asm volatile("s_waitcnt vmcnt(4) lgkmcnt(0)" ::: "memory");  // B(p+1) landed
      } else {
        asm volatile("s_waitcnt vmcnt(0) lgkmcnt(0)" ::: "memory");  // drain last
      }
      __builtin_amdgcn_s_barrier();
      __builtin_amdgcn_sched_barrier(0);
    }
  }

  // epilogue: bf16 partials
  unsigned short* po = part + (size_t)ks * ((size_t)Bsz * OUTsz);
  const int r0 = brow + wr * 128 + ((lane >> 4) * 4);
  const int c0 = bcol + wc * 64 + (lane & 15);
#pragma unroll
  for (int m = 0; m < 8; ++m)
#pragma unroll
    for (int q = 0; q < 4; ++q)
#pragma unroll
      for (int e = 0; e < 4; ++e)
        po[(size_t)(r0 + m * 16 + e) * OUTsz + (c0 + q * 16)] = f2bf(acc[m][q][e]);
}

// ---- reduce 8 bf16 split-K partials + bias + kl ----
__global__ __launch_bounds__(256) void reduce_kernel(
    const unsigned short* __restrict__ part, const float* __restrict__ bias,
    float* __restrict__ out) {
  const size_t idx  = (size_t)blockIdx.x * 256 + threadIdx.x;  // unit = 8 outputs
  const size_t base = idx * 8;
  float s[8];
#pragma unroll
  for (int e = 0; e < 8; ++e) s[e] = 0.0f;
#pragma unroll
  for (int sp = 0; sp < SPLITK; ++sp) {
    short8 v = *reinterpret_cast<const short8*>(part + sp * ((size_t)Bsz * OUTsz) + base);
#pragma unroll
    for (int e = 0; e < 8; ++e) s[e] += bf2f((unsigned short)v[e]);
  }
  const int ob = (int)(base & (OUTsz - 1));
  f32x4 b0 = *reinterpret_cast<const f32x4*>(bias + ob);
  f32x4 b1 = *reinterpret_cast<const f32x4*>(bias + ob + 4);
  f32x4 o0 = { s[0] + b0[0], s[1] + b0[1], s[2] + b0[2], s[3] + b0[3] };
  f32x4 o1 = { s[4] + b1[0], s[5] + b1[1], s[6] + b1[2], s[7] + b1[3] };
  *reinterpret_cast<f32x4*>(out + base) = o0;
  *reinterpret_cast<f32x4*>(out + base + 4) = o1;
  if (idx == 0) out[(size_t)Bsz * OUTsz] = 0.0f;   // kl
}

extern "C" void kernel_launch(void* const* d_in, const int* in_sizes, int n_in,
                              void* d_out, int out_size, void* d_ws, size_t ws_size,
                              hipStream_t stream) {
  const float* x      = (const float*)d_in[0];
  const float* coeffs = (const float*)d_in[1];
  const float* bw     = (const float*)d_in[2];
  float* out = (float*)d_out;

  unsigned short* Bt   = (unsigned short*)d_ws;                            // 8,912,896 B
  unsigned short* part = (unsigned short*)((char*)d_ws + (size_t)OUTsz * KTOT * 2);  // 33,554,432 B
  float* bias = (float*)((char*)d_ws + (size_t)OUTsz * KTOT * 2
                                     + (size_t)SPLITK * Bsz * OUTsz * 2);  // 2048 B

  RC rc;
  float PQ;
  {
    const double PI  = 3.14159265358979323846;
    const double Lc  = 2.0 * PI * 30.0e-6;
    const double WL0 = 1550.0e-9;
    const double NG  = 4.2;
    const double Aamp = pow(10.0, -3.0 * (Lc * 100.0) / 20.0);
    const double Rt2  = 0.8;
    const double Rt   = sqrt(Rt2);
    for (int rr = 0; rr < NRING; ++rr) {
      double off  = -PI + rr * (2.0 * PI / 15.0);
      double neff = 2.34 + off * WL0 / (2.0 * PI * Lc);
      double rev0 = (Lc / WL0) * neff;
      rc.Fr[rr] = (float)(rev0 - floor(rev0));
    }
    const double qn = -2.0 * Rt * Aamp;
    const double s  = 1.0 + Rt2 * Aamp * Aamp;
    const double P  = -(1.0 - Aamp * Aamp) * (1.0 - Rt2);
    rc.K2 = (float)(-4.0e-9 * Lc * NG / WL0);
    rc.SQ = (float)(s / qn);
    rc.pad0 = rc.pad1 = 0.f;
    PQ = (float)(P / qn);
  }

  hipFuncSetAttribute(reinterpret_cast<const void*>(gemm_fused_kernel),
                      hipFuncAttributeMaxDynamicSharedMemorySize, 163840);

  hipLaunchKernelGGL(pack_b_kernel, dim3(OUTsz), dim3(512), 0, stream,
                     coeffs, bw, Bt, bias, PQ);
  hipLaunchKernelGGL(gemm_fused_kernel, dim3(256), dim3(512), 163840, stream,
                     x, Bt, part, rc);
  hipLaunchKernelGGL(reduce_kernel, dim3((Bsz * OUTsz / 8) / 256), dim3(256), 0, stream,
                     part, bias, out);
}